// Round 9
// baseline (429.839 us; speedup 1.0000x reference)
//
#include <hip/hip_runtime.h>

// GCN: 2x GCNConv(+self-loop sym-norm) + ReLU, global mean pool, linear head.
// N=100000, E=1600000, G=100, D_IN=3, H=128, OUT=10.
//
// R8->R9: (1) packed dual-fp32 (float2 ext-vector -> v_pk_fma_f32) in
// agg2pool phases A+B, __launch_bounds__(256,4) for VGPR headroom (R8
// compiled at 48 VGPRs). (2) Phase A balance: 16-lane group owns 4
// CONSECUTIVE nodes (contiguous CSR edge span) -> barrier waits on
// sum-of-4-degrees (±12%) not single-degree max (1.6x). MPB=64.
// (3) Tail: scan3 folded into scan1 (dinvs+scale) and fill (+partials at
// use); xf as float4 with dinvs in .w (1 load/edge in aggu); fill 4
// edges/thread via int4. 10 -> 8 dispatches.
//
// All kernels static + gcn364_ prefix (cross-.so symbol collisions caused the
// round-1 silent failure). Runtime dtype probe handles bf16/fp32 harness mode.

#define DIN 3
#define H 128
#define OUTF 10
#define NWEIGHT (384 + 128 + 16384 + 128 + 1280 + 10)  // W1,b1,W2,b2,Wl,bl

typedef float gcn364_f2 __attribute__((ext_vector_type(2)));

__device__ __forceinline__ float gcn364_bf2f(unsigned short u) {
    return __uint_as_float(((unsigned int)u) << 16);
}
__device__ __forceinline__ unsigned short gcn364_f2bf(float f) {
    unsigned int u = __float_as_uint(f);
    u += 0x7FFFu + ((u >> 16) & 1u);   // round-to-nearest-even
    return (unsigned short)(u >> 16);
}

// ---- dtype probe: flag=1 if x is fp32, flag=0 if bf16 ----
static __global__ void gcn364_detect(const unsigned short* __restrict__ xraw,
                                     int* __restrict__ flag) {
    __shared__ int cnt;
    if (threadIdx.x == 0) cnt = 0;
    __syncthreads();
    unsigned short u = xraw[threadIdx.x];
    int e = (u >> 7) & 0xFF;
    int outlier = (e < 100 || e > 140) ? 1 : 0;
    atomicAdd(&cnt, outlier);
    __syncthreads();
    if (threadIdx.x == 0) *flag = (cnt > 32) ? 1 : 0;
}

// ---- convert x -> xf4 (float4/node, .w=0) + weights -> wf + deg count ----
static __global__ void gcn364_convdeg(const void* __restrict__ x,
                                      const void* __restrict__ W1, const void* __restrict__ b1,
                                      const void* __restrict__ W2, const void* __restrict__ b2,
                                      const void* __restrict__ Wl, const void* __restrict__ bl,
                                      const int* __restrict__ flag,
                                      float4* __restrict__ xf4, float* __restrict__ wf,
                                      const int* __restrict__ edst, int* __restrict__ deg,
                                      int N, int E) {
    int i = blockIdx.x * blockDim.x + threadIdx.x;
    if (i < E) atomicAdd(&deg[edst[i]], 1);
    int fl = *flag;
    if (i < N) {
        float a, b, c;
        if (fl) {
            const float* xs = (const float*)x;
            a = xs[3 * i]; b = xs[3 * i + 1]; c = xs[3 * i + 2];
        } else {
            const unsigned short* xs = (const unsigned short*)x;
            a = gcn364_bf2f(xs[3 * i]); b = gcn364_bf2f(xs[3 * i + 1]); c = gcn364_bf2f(xs[3 * i + 2]);
        }
        xf4[i] = make_float4(a, b, c, 0.f);
    } else if (i < N + NWEIGHT) {
        int j = i - N;
        const void* srcp;
        if      (j < 384)                       { srcp = W1; }
        else if ((j -= 384)   < 128)            { srcp = b1; }
        else if ((j -= 128)   < 16384)          { srcp = W2; }
        else if ((j -= 16384) < 128)            { srcp = b2; }
        else if ((j -= 128)   < 1280)           { srcp = Wl; }
        else    { j -= 1280;                      srcp = bl; }
        wf[i - N] = fl ? ((const float*)srcp)[j]
                       : gcn364_bf2f(((const unsigned short*)srcp)[j]);
    }
}

// ---- exclusive scan of deg[N] -> off[N] (block-local) + dinvs/xf scaling ----
static __global__ void gcn364_scan1(const int* __restrict__ deg, int* __restrict__ off,
                                    int* __restrict__ partials, float4* __restrict__ xf4,
                                    int N) {
    __shared__ int sh[256];
    int t = threadIdx.x;
    int base = blockIdx.x * 1024 + t * 4;
    int v0 = (base + 0 < N) ? deg[base + 0] : 0;
    int v1 = (base + 1 < N) ? deg[base + 1] : 0;
    int v2 = (base + 2 < N) ? deg[base + 2] : 0;
    int v3 = (base + 3 < N) ? deg[base + 3] : 0;
    int s = v0 + v1 + v2 + v3;
    sh[t] = s;
    __syncthreads();
    for (int d = 1; d < 256; d <<= 1) {
        int val = (t >= d) ? sh[t - d] : 0;
        __syncthreads();
        sh[t] += val;
        __syncthreads();
    }
    int excl = sh[t] - s;
    int run = excl;
    if (base + 0 < N) off[base + 0] = run; run += v0;
    if (base + 1 < N) off[base + 1] = run; run += v1;
    if (base + 2 < N) off[base + 2] = run; run += v2;
    if (base + 3 < N) off[base + 3] = run;
    if (t == 255) partials[blockIdx.x] = sh[255];
    // dinvs + pre-scale xf by dinvs; dinvs rides in xf4.w
    int vv[4] = {v0, v1, v2, v3};
    #pragma unroll
    for (int k = 0; k < 4; k++) {
        int i = base + k;
        if (i < N) {
            float di = rsqrtf((float)vv[k] + 1.0f);
            float4 xv = xf4[i];
            xv.x *= di; xv.y *= di; xv.z *= di; xv.w = di;
            xf4[i] = xv;
        }
    }
}

// block 0: scan of partials; block 1: nodes-per-graph via binary search
static __global__ void gcn364_scan2cnt(int* __restrict__ partials, int nb,
                                       const int* __restrict__ batch,
                                       float* __restrict__ cnt, int N, int G) {
    if (blockIdx.x == 0) {
        __shared__ int sh[256];
        int t = threadIdx.x;
        int v = (t < nb) ? partials[t] : 0;
        sh[t] = v;
        __syncthreads();
        for (int d = 1; d < 256; d <<= 1) {
            int val = (t >= d) ? sh[t - d] : 0;
            __syncthreads();
            sh[t] += val;
            __syncthreads();
        }
        if (t < nb) partials[t] = sh[t] - v;   // exclusive
    } else {
        for (int g = threadIdx.x; g < G; g += blockDim.x) {
            int lo = 0, hi = N;
            while (lo < hi) { int m = (lo + hi) >> 1; if (batch[m] < g) lo = m + 1; else hi = m; }
            int a = lo;
            lo = 0; hi = N;
            while (lo < hi) { int m = (lo + hi) >> 1; if (batch[m] < g + 1) lo = m + 1; else hi = m; }
            cnt[g] = (float)(lo - a);
        }
    }
}

// bucket fill, 4 edges/thread; position = local cursor + partials at use.
// Afterwards off[i] + partials[i>>10] == end offset of node i.
static __global__ void gcn364_fill(const int* __restrict__ src, const int* __restrict__ dst,
                                   int* __restrict__ off, const int* __restrict__ partials,
                                   int* __restrict__ esrc, int E) {
    int t = blockIdx.x * blockDim.x + threadIdx.x;
    int e0 = t * 4;
    if (e0 >= E) return;
    bool aligned = ((((size_t)src) | ((size_t)dst)) & 15) == 0;
    if (aligned && e0 + 3 < E) {
        int4 s = *(const int4*)(src + e0);
        int4 d = *(const int4*)(dst + e0);
        int p;
        p = atomicAdd(&off[d.x], 1) + partials[d.x >> 10]; esrc[p] = s.x;
        p = atomicAdd(&off[d.y], 1) + partials[d.y >> 10]; esrc[p] = s.y;
        p = atomicAdd(&off[d.z], 1) + partials[d.z >> 10]; esrc[p] = s.z;
        p = atomicAdd(&off[d.w], 1) + partials[d.w >> 10]; esrc[p] = s.w;
    } else {
        for (int e = e0; e < E && e < e0 + 4; e++) {
            int d = dst[e];
            int p = atomicAdd(&off[d], 1) + partials[d >> 10];
            esrc[p] = src[e];
        }
    }
}

// Layer-1 aggregation -> u4 records. 16 lanes per node, 4 nodes per wave.
// xf4 pre-scaled by dinvs (dinvs in .w). One float4 load per edge.
static __global__ void gcn364_aggu(const int* __restrict__ esrc,
                                   const int* __restrict__ off,
                                   const int* __restrict__ partials,
                                   const float4* __restrict__ xf4,
                                   float4* __restrict__ u4, int N) {
    int lane = threadIdx.x & 63;
    int wv = threadIdx.x >> 6;
    int grp = lane >> 4;
    int sub = lane & 15;
    int i = (blockIdx.x * 4 + wv) * 4 + grp;

    float a0 = 0.f, a1 = 0.f, a2 = 0.f;
    if (i < N) {
        int p0 = (i == 0) ? 0 : off[i - 1] + partials[(i - 1) >> 10];
        int p1 = off[i] + partials[i >> 10];
        for (int p = p0 + sub; p < p1; p += 16) {
            float4 sv = xf4[esrc[p]];
            a0 += sv.x; a1 += sv.y; a2 += sv.z;
        }
    }
    for (int d = 1; d < 16; d <<= 1) {
        a0 += __shfl_xor(a0, d);
        a1 += __shfl_xor(a1, d);
        a2 += __shfl_xor(a2, d);
    }
    if (i < N && sub == 0) {
        float4 xi = xf4[i];
        float di = xi.w;
        u4[i] = make_float4(di * (a0 + xi.x), di * (a1 + xi.y), di * (a2 + xi.z), di);
    }
}

// per-edge layer-1 row recompute + accumulate (packed dual-fp32)
__device__ __forceinline__ void gcn364_edge(const float4 u,
                                            const gcn364_f2* wa2, const gcn364_f2* wb2,
                                            const gcn364_f2* wc2, const gcn364_f2* bb2,
                                            gcn364_f2* acc) {
    gcn364_f2 ux = {u.x, u.x}, uy = {u.y, u.y}, uz = {u.z, u.z}, uw = {u.w, u.w};
    gcn364_f2 zero = {0.f, 0.f};
    #pragma unroll
    for (int q = 0; q < 4; q++) {
        gcn364_f2 t = ux * wa2[q] + uy * wb2[q] + uz * wc2[q] + bb2[q];
        t = __builtin_elementwise_max(t, zero);
        acc[q] += uw * t;
    }
}

// Fused layer-2: per-edge on-the-fly layer-1 recompute + aggregation + GEMM +
// relu + mean-pool. MPB=64 nodes/block, 256 thr = 16 groups x 16 lanes.
// Phase A: group owns 4 CONSECUTIVE nodes (balanced: sum of 4 degrees).
// Phase B: 4 chunks of 16 nodes, packed-fp32 GEMM, grouped pooled atomics.
#define MPB 64
static __global__ __launch_bounds__(256, 4) void gcn364_agg2pool(
        const int* __restrict__ esrc, const int* __restrict__ off,
        const int* __restrict__ partials, const float4* __restrict__ u4,
        const float* __restrict__ w1f, const float* __restrict__ b1f,
        const float* __restrict__ w2f, const float* __restrict__ b2f,
        const int* __restrict__ batch, float* __restrict__ pooled, int N) {
    __shared__ float vsh[MPB][H];
    int i0 = blockIdx.x * MPB;
    int tid = threadIdx.x;
    int wave = tid >> 6;
    int lane = tid & 63;
    int grp = lane >> 4;
    int sub = lane & 15;
    int gq = wave * 4 + grp;          // 0..15, owns nodes i0+4gq .. +3

    gcn364_f2 wa2[4], wb2[4], wc2[4], bb2[4];
    #pragma unroll
    for (int q = 0; q < 4; q++) {
        int f = sub * 8 + q * 2;
        wa2[q] = (gcn364_f2){w1f[f], w1f[f + 1]};
        wb2[q] = (gcn364_f2){w1f[H + f], w1f[H + f + 1]};
        wc2[q] = (gcn364_f2){w1f[2 * H + f], w1f[2 * H + f + 1]};
        bb2[q] = (gcn364_f2){b1f[f], b1f[f + 1]};
    }

    for (int c = 0; c < 4; c++) {
        int i = i0 + gq * 4 + c;
        gcn364_f2 acc[4];
        acc[0] = acc[1] = acc[2] = acc[3] = (gcn364_f2){0.f, 0.f};
        float di = 0.f;
        if (i < N) {
            int p0 = (i == 0) ? 0 : off[i - 1] + partials[(i - 1) >> 10];
            int p1 = off[i] + partials[i >> 10];
            int p = p0;
            for (; p + 2 <= p1; p += 2) {
                float4 uA = u4[esrc[p]];
                float4 uB = u4[esrc[p + 1]];
                gcn364_edge(uA, wa2, wb2, wc2, bb2, acc);
                gcn364_edge(uB, wa2, wb2, wc2, bb2, acc);
            }
            if (p < p1) {
                float4 uA = u4[esrc[p]];
                gcn364_edge(uA, wa2, wb2, wc2, bb2, acc);
            }
            float4 uS = u4[i];   // self-loop
            gcn364_edge(uS, wa2, wb2, wc2, bb2, acc);
            di = uS.w;
        }
        *(float4*)&vsh[gq * 4 + c][sub * 8 + 0] =
            make_float4(acc[0].x * di, acc[0].y * di, acc[1].x * di, acc[1].y * di);
        *(float4*)&vsh[gq * 4 + c][sub * 8 + 4] =
            make_float4(acc[2].x * di, acc[2].y * di, acc[3].x * di, acc[3].y * di);
    }
    __syncthreads();

    int f = tid & (H - 1);
    int half = tid >> 7;
    float bb = b2f[f];
    for (int t = 0; t < 4; t++) {
        gcn364_f2 a2[8];
        #pragma unroll
        for (int n = 0; n < 8; n++) a2[n] = (gcn364_f2){0.f, 0.f};
        for (int k4 = 0; k4 < H / 4; k4++) {
            float w0 = w2f[(k4 * 4 + 0) * H + f];
            float w1 = w2f[(k4 * 4 + 1) * H + f];
            float w2v = w2f[(k4 * 4 + 2) * H + f];
            float w3 = w2f[(k4 * 4 + 3) * H + f];
            gcn364_f2 wlo = {w0, w1}, whi = {w2v, w3};
            #pragma unroll
            for (int n = 0; n < 8; n++) {
                float4 v = *(const float4*)&vsh[t * 16 + 2 * n + half][k4 * 4];
                a2[n] += (gcn364_f2){v.x, v.y} * wlo + (gcn364_f2){v.z, v.w} * whi;
            }
        }
        float sum = 0.0f;
        int curg = -1;
        #pragma unroll
        for (int j = 0; j < 8; j++) {
            int ii = i0 + t * 16 + half + 2 * j;
            if (ii >= N) continue;
            float val = fmaxf(a2[j].x + a2[j].y + bb, 0.0f);
            int g = batch[ii];
            if (g != curg) {
                if (curg >= 0) atomicAdd(&pooled[curg * H + f], sum);
                curg = g;
                sum = 0.0f;
            }
            sum += val;
        }
        if (curg >= 0) atomicAdd(&pooled[curg * H + f], sum);
    }
}

// out[g] = (pooled[g]/max(cnt,1)) @ Wl + bl  -> detected dtype
static __global__ void gcn364_final(const float* __restrict__ pooled,
                                    const float* __restrict__ cnt,
                                    const float* __restrict__ wlf,
                                    const float* __restrict__ blf,
                                    const int* __restrict__ flag,
                                    void* __restrict__ out, int G) {
    int g = blockIdx.x;
    int o = threadIdx.x;
    if (g >= G || o >= OUTF) return;
    float inv = 1.0f / fmaxf(cnt[g], 1.0f);
    float acc = 0.0f;
    for (int k = 0; k < H; k++)
        acc += pooled[g * H + k] * wlf[k * OUTF + o];
    float v = acc * inv + blf[o];
    if (*flag) ((float*)out)[g * OUTF + o] = v;
    else       ((unsigned short*)out)[g * OUTF + o] = gcn364_f2bf(v);
}

extern "C" void kernel_launch(void* const* d_in, const int* in_sizes, int n_in,
                              void* d_out, int out_size, void* d_ws, size_t ws_size,
                              hipStream_t stream) {
    const void* x  = d_in[0];
    const int* edge_index = (const int*)d_in[1];
    const int* batch      = (const int*)d_in[2];
    const void* W1 = d_in[3];
    const void* b1 = d_in[4];
    const void* W2 = d_in[5];
    const void* b2 = d_in[6];
    const void* Wl = d_in[7];
    const void* bl = d_in[8];

    const int N = in_sizes[0] / DIN;
    const int E = in_sizes[1] / 2;
    const int G = out_size / OUTF;
    const int* src = edge_index;
    const int* dst = edge_index + E;
    const int NB = (N + 1023) / 1024;   // scan blocks (must be <= 256)

    // ---- workspace layout; deg+pooled zeroed (contiguous at ws start) ----
    char* wsb = (char*)d_ws;
    int*   deg      = (int*)wsb;                                  // N      (zeroed)
    float* pooled   = (float*)(deg + N);                          // G*H    (zeroed)
    int*   off      = (int*)(pooled + (size_t)G * H);             // N
    int*   partials = off + N;                                    // 256
    float* cnt      = (float*)(partials + 256);                   // G
    int*   flag     = (int*)(cnt + G);                            // 1
    size_t ofs = (((size_t)((char*)(flag + 1) - wsb)) + 15) & ~(size_t)15;
    float4* xf4 = (float4*)(wsb + ofs);                           // N float4
    float4* u4  = xf4 + N;                                        // N float4
    float* wf   = (float*)(u4 + N);                               // NWEIGHT
    int*   esrc = (int*)(wf + NWEIGHT);                           // E

    float* w1f = wf;
    float* b1f = w1f + 384;
    float* w2f = b1f + 128;
    float* b2f = w2f + 16384;
    float* wlf = b2f + 128;
    float* blf = wlf + 1280;

    hipMemsetAsync(d_ws, 0, ((size_t)N + (size_t)G * H) * 4, stream);

    gcn364_detect<<<1, 256, 0, stream>>>((const unsigned short*)x, flag);
    {
        int total = N + NWEIGHT;
        int gmax = (E > total) ? E : total;
        gcn364_convdeg<<<(gmax + 255) / 256, 256, 0, stream>>>(
            x, W1, b1, W2, b2, Wl, bl, flag, xf4, wf, dst, deg, N, E);
    }
    gcn364_scan1<<<NB, 256, 0, stream>>>(deg, off, partials, xf4, N);
    gcn364_scan2cnt<<<2, 256, 0, stream>>>(partials, NB, batch, cnt, N, G);
    {
        int nthr = (E + 3) / 4;
        gcn364_fill<<<(nthr + 255) / 256, 256, 0, stream>>>(src, dst, off, partials, esrc, E);
    }
    gcn364_aggu<<<(N + 15) / 16, 256, 0, stream>>>(esrc, off, partials, xf4, u4, N);
    gcn364_agg2pool<<<(N + MPB - 1) / MPB, 256, 0, stream>>>(
        esrc, off, partials, u4, w1f, b1f, w2f, b2f, batch, pooled, N);
    gcn364_final<<<G, 64, 0, stream>>>(pooled, cnt, wlf, blf, flag, d_out, G);
}

// Round 10
// 414.473 us; speedup vs baseline: 1.0371x; 1.0371x over previous
//
#include <hip/hip_runtime.h>

// GCN: 2x GCNConv(+self-loop sym-norm) + ReLU, global mean pool, linear head.
// N=100000, E=1600000, G=100, D_IN=3, H=128, OUT=10.
//
// R9->R10: (1) agg2pool back to MPB=16 / group-per-node (R8's 48%-occupancy
// config; R9's MPB=64+32KB LDS dropped occupancy to 31% and went latency
// bound) while KEEPING R9's packed dual-fp32 math (validated: VALUBusy 83->52
// at equal VALU work). __launch_bounds__(256,8). (2) detect kernel removed:
// each convdeg wave probes dtype itself (L2-broadcast loads + 6 shuffles) and
// publishes the flag for final. (3) cnt binary search folded into final.
// 9 -> 7 graph dispatches.
//
// All kernels static + gcn364_ prefix (cross-.so symbol collisions caused the
// round-1 silent failure). Runtime dtype probe handles bf16/fp32 harness mode.

#define DIN 3
#define H 128
#define OUTF 10
#define NWEIGHT (384 + 128 + 16384 + 128 + 1280 + 10)  // W1,b1,W2,b2,Wl,bl

typedef float gcn364_f2 __attribute__((ext_vector_type(2)));

__device__ __forceinline__ float gcn364_bf2f(unsigned short u) {
    return __uint_as_float(((unsigned int)u) << 16);
}
__device__ __forceinline__ unsigned short gcn364_f2bf(float f) {
    unsigned int u = __float_as_uint(f);
    u += 0x7FFFu + ((u >> 16) & 1u);   // round-to-nearest-even
    return (unsigned short)(u >> 16);
}

// per-wave dtype probe over x's first 256 ushorts: 1 -> fp32, 0 -> bf16.
// bf16 N(0,1) exponents cluster in [101,129]; fp32 low-halves are ~uniform.
__device__ __forceinline__ int gcn364_probe(const unsigned short* __restrict__ xs16) {
    int lane = threadIdx.x & 63;
    int outl = 0;
    #pragma unroll
    for (int k = 0; k < 4; k++) {
        unsigned short u = xs16[lane * 4 + k];
        int e = (u >> 7) & 0xFF;
        outl += (e < 100 || e > 140) ? 1 : 0;
    }
    #pragma unroll
    for (int d = 1; d < 64; d <<= 1) outl += __shfl_xor(outl, d);
    return (outl > 32) ? 1 : 0;
}

// ---- convert x -> xf4 (float4/node) + weights -> wf + deg count + flag ----
static __global__ void gcn364_convdeg(const void* __restrict__ x,
                                      const void* __restrict__ W1, const void* __restrict__ b1,
                                      const void* __restrict__ W2, const void* __restrict__ b2,
                                      const void* __restrict__ Wl, const void* __restrict__ bl,
                                      int* __restrict__ flag,
                                      float4* __restrict__ xf4, float* __restrict__ wf,
                                      const int* __restrict__ edst, int* __restrict__ deg,
                                      int N, int E) {
    int fl = gcn364_probe((const unsigned short*)x);
    int i = blockIdx.x * blockDim.x + threadIdx.x;
    if (i == 0) *flag = fl;
    if (i < E) atomicAdd(&deg[edst[i]], 1);
    if (i < N) {
        float a, b, c;
        if (fl) {
            const float* xs = (const float*)x;
            a = xs[3 * i]; b = xs[3 * i + 1]; c = xs[3 * i + 2];
        } else {
            const unsigned short* xs = (const unsigned short*)x;
            a = gcn364_bf2f(xs[3 * i]); b = gcn364_bf2f(xs[3 * i + 1]); c = gcn364_bf2f(xs[3 * i + 2]);
        }
        xf4[i] = make_float4(a, b, c, 0.f);
    } else if (i < N + NWEIGHT) {
        int j = i - N;
        const void* srcp;
        if      (j < 384)                       { srcp = W1; }
        else if ((j -= 384)   < 128)            { srcp = b1; }
        else if ((j -= 128)   < 16384)          { srcp = W2; }
        else if ((j -= 16384) < 128)            { srcp = b2; }
        else if ((j -= 128)   < 1280)           { srcp = Wl; }
        else    { j -= 1280;                      srcp = bl; }
        wf[i - N] = fl ? ((const float*)srcp)[j]
                       : gcn364_bf2f(((const unsigned short*)srcp)[j]);
    }
}

// ---- exclusive scan of deg[N] -> off[N] (block-local) + dinvs/xf scaling ----
static __global__ void gcn364_scan1(const int* __restrict__ deg, int* __restrict__ off,
                                    int* __restrict__ partials, float4* __restrict__ xf4,
                                    int N) {
    __shared__ int sh[256];
    int t = threadIdx.x;
    int base = blockIdx.x * 1024 + t * 4;
    int v0 = (base + 0 < N) ? deg[base + 0] : 0;
    int v1 = (base + 1 < N) ? deg[base + 1] : 0;
    int v2 = (base + 2 < N) ? deg[base + 2] : 0;
    int v3 = (base + 3 < N) ? deg[base + 3] : 0;
    int s = v0 + v1 + v2 + v3;
    sh[t] = s;
    __syncthreads();
    for (int d = 1; d < 256; d <<= 1) {
        int val = (t >= d) ? sh[t - d] : 0;
        __syncthreads();
        sh[t] += val;
        __syncthreads();
    }
    int excl = sh[t] - s;
    int run = excl;
    if (base + 0 < N) off[base + 0] = run; run += v0;
    if (base + 1 < N) off[base + 1] = run; run += v1;
    if (base + 2 < N) off[base + 2] = run; run += v2;
    if (base + 3 < N) off[base + 3] = run;
    if (t == 255) partials[blockIdx.x] = sh[255];
    // dinvs + pre-scale xf by dinvs; dinvs rides in xf4.w
    int vv[4] = {v0, v1, v2, v3};
    #pragma unroll
    for (int k = 0; k < 4; k++) {
        int i = base + k;
        if (i < N) {
            float di = rsqrtf((float)vv[k] + 1.0f);
            float4 xv = xf4[i];
            xv.x *= di; xv.y *= di; xv.z *= di; xv.w = di;
            xf4[i] = xv;
        }
    }
}

// single block: exclusive scan of per-block partials
static __global__ void gcn364_scan2(int* __restrict__ partials, int nb) {
    __shared__ int sh[256];
    int t = threadIdx.x;
    int v = (t < nb) ? partials[t] : 0;
    sh[t] = v;
    __syncthreads();
    for (int d = 1; d < 256; d <<= 1) {
        int val = (t >= d) ? sh[t - d] : 0;
        __syncthreads();
        sh[t] += val;
        __syncthreads();
    }
    if (t < nb) partials[t] = sh[t] - v;   // exclusive
}

// bucket fill; position = local cursor + partials at use.
// Afterwards off[i] + partials[i>>10] == end offset of node i.
static __global__ void gcn364_fill(const int* __restrict__ src, const int* __restrict__ dst,
                                   int* __restrict__ off, const int* __restrict__ partials,
                                   int* __restrict__ esrc, int E) {
    int e = blockIdx.x * blockDim.x + threadIdx.x;
    if (e >= E) return;
    int d = dst[e];
    int p = atomicAdd(&off[d], 1) + partials[d >> 10];
    esrc[p] = src[e];
}

// Layer-1 aggregation -> u4 records. 16 lanes per node, 4 nodes per wave.
// xf4 pre-scaled by dinvs (dinvs in .w). One float4 load per edge.
static __global__ void gcn364_aggu(const int* __restrict__ esrc,
                                   const int* __restrict__ off,
                                   const int* __restrict__ partials,
                                   const float4* __restrict__ xf4,
                                   float4* __restrict__ u4, int N) {
    int lane = threadIdx.x & 63;
    int wv = threadIdx.x >> 6;
    int grp = lane >> 4;
    int sub = lane & 15;
    int i = (blockIdx.x * 4 + wv) * 4 + grp;

    float a0 = 0.f, a1 = 0.f, a2 = 0.f;
    if (i < N) {
        int p0 = (i == 0) ? 0 : off[i - 1] + partials[(i - 1) >> 10];
        int p1 = off[i] + partials[i >> 10];
        for (int p = p0 + sub; p < p1; p += 16) {
            float4 sv = xf4[esrc[p]];
            a0 += sv.x; a1 += sv.y; a2 += sv.z;
        }
    }
    for (int d = 1; d < 16; d <<= 1) {
        a0 += __shfl_xor(a0, d);
        a1 += __shfl_xor(a1, d);
        a2 += __shfl_xor(a2, d);
    }
    if (i < N && sub == 0) {
        float4 xi = xf4[i];
        float di = xi.w;
        u4[i] = make_float4(di * (a0 + xi.x), di * (a1 + xi.y), di * (a2 + xi.z), di);
    }
}

// per-edge layer-1 row recompute + accumulate (packed dual-fp32)
__device__ __forceinline__ void gcn364_edge(const float4 u,
                                            const gcn364_f2* wa2, const gcn364_f2* wb2,
                                            const gcn364_f2* wc2, const gcn364_f2* bb2,
                                            gcn364_f2* acc) {
    gcn364_f2 ux = {u.x, u.x}, uy = {u.y, u.y}, uz = {u.z, u.z}, uw = {u.w, u.w};
    gcn364_f2 zero = {0.f, 0.f};
    #pragma unroll
    for (int q = 0; q < 4; q++) {
        gcn364_f2 t = ux * wa2[q] + uy * wb2[q] + uz * wc2[q] + bb2[q];
        t = __builtin_elementwise_max(t, zero);
        acc[q] += uw * t;
    }
}

// Fused layer-2: per-edge on-the-fly layer-1 recompute + aggregation + GEMM +
// relu + mean-pool. MPB=16 nodes/block, 256 thr = 16 groups x 16 lanes,
// group-per-node (R8 tiling), packed dual-fp32 (R9 math).
#define MPB 16
static __global__ __launch_bounds__(256, 8) void gcn364_agg2pool(
        const int* __restrict__ esrc, const int* __restrict__ off,
        const int* __restrict__ partials, const float4* __restrict__ u4,
        const float* __restrict__ w1f, const float* __restrict__ b1f,
        const float* __restrict__ w2f, const float* __restrict__ b2f,
        const int* __restrict__ batch, float* __restrict__ pooled, int N) {
    __shared__ float vsh[MPB][H];
    int i0 = blockIdx.x * MPB;
    int tid = threadIdx.x;
    int wave = tid >> 6;
    int lane = tid & 63;
    int grp = lane >> 4;
    int sub = lane & 15;
    int node = wave * 4 + grp;
    int i = i0 + node;

    gcn364_f2 wa2[4], wb2[4], wc2[4], bb2[4];
    #pragma unroll
    for (int q = 0; q < 4; q++) {
        int f = sub * 8 + q * 2;
        wa2[q] = (gcn364_f2){w1f[f], w1f[f + 1]};
        wb2[q] = (gcn364_f2){w1f[H + f], w1f[H + f + 1]};
        wc2[q] = (gcn364_f2){w1f[2 * H + f], w1f[2 * H + f + 1]};
        bb2[q] = (gcn364_f2){b1f[f], b1f[f + 1]};
    }

    gcn364_f2 acc[4];
    acc[0] = acc[1] = acc[2] = acc[3] = (gcn364_f2){0.f, 0.f};
    float di = 0.f;
    if (i < N) {
        int p0 = (i == 0) ? 0 : off[i - 1] + partials[(i - 1) >> 10];
        int p1 = off[i] + partials[i >> 10];
        int p = p0;
        for (; p + 2 <= p1; p += 2) {
            float4 uA = u4[esrc[p]];
            float4 uB = u4[esrc[p + 1]];
            gcn364_edge(uA, wa2, wb2, wc2, bb2, acc);
            gcn364_edge(uB, wa2, wb2, wc2, bb2, acc);
        }
        if (p < p1) {
            float4 uA = u4[esrc[p]];
            gcn364_edge(uA, wa2, wb2, wc2, bb2, acc);
        }
        float4 uS = u4[i];   // self-loop
        gcn364_edge(uS, wa2, wb2, wc2, bb2, acc);
        di = uS.w;
    }
    *(float4*)&vsh[node][sub * 8 + 0] =
        make_float4(acc[0].x * di, acc[0].y * di, acc[1].x * di, acc[1].y * di);
    *(float4*)&vsh[node][sub * 8 + 4] =
        make_float4(acc[2].x * di, acc[2].y * di, acc[3].x * di, acc[3].y * di);
    __syncthreads();

    int f = tid & (H - 1);
    int half = tid >> 7;
    float bb = b2f[f];
    gcn364_f2 a2[8];
    #pragma unroll
    for (int n = 0; n < 8; n++) a2[n] = (gcn364_f2){0.f, 0.f};
    for (int k4 = 0; k4 < H / 4; k4++) {
        gcn364_f2 wlo = {w2f[(k4 * 4 + 0) * H + f], w2f[(k4 * 4 + 1) * H + f]};
        gcn364_f2 whi = {w2f[(k4 * 4 + 2) * H + f], w2f[(k4 * 4 + 3) * H + f]};
        #pragma unroll
        for (int n = 0; n < 8; n++) {
            float4 v = *(const float4*)&vsh[2 * n + half][k4 * 4];
            a2[n] += (gcn364_f2){v.x, v.y} * wlo + (gcn364_f2){v.z, v.w} * whi;
        }
    }

    float sum = 0.0f;
    int curg = -1;
    #pragma unroll
    for (int j = 0; j < 8; j++) {
        int ii = i0 + half + 2 * j;
        if (ii >= N) continue;
        float val = fmaxf(a2[j].x + a2[j].y + bb, 0.0f);
        int g = batch[ii];
        if (g != curg) {
            if (curg >= 0) atomicAdd(&pooled[curg * H + f], sum);
            curg = g;
            sum = 0.0f;
        }
        sum += val;
    }
    if (curg >= 0) atomicAdd(&pooled[curg * H + f], sum);
}

// out[g] = (pooled[g]/cnt_g) @ Wl + bl  -> detected dtype.
// cnt_g computed here via binary search on the sorted batch array.
static __global__ void gcn364_final(const float* __restrict__ pooled,
                                    const int* __restrict__ batch,
                                    const float* __restrict__ wlf,
                                    const float* __restrict__ blf,
                                    const int* __restrict__ flag,
                                    void* __restrict__ out, int N, int G) {
    int g = blockIdx.x;
    int o = threadIdx.x;
    if (g >= G || o >= OUTF) return;
    int lo = 0, hi = N;
    while (lo < hi) { int m = (lo + hi) >> 1; if (batch[m] < g) lo = m + 1; else hi = m; }
    int a = lo;
    lo = 0; hi = N;
    while (lo < hi) { int m = (lo + hi) >> 1; if (batch[m] < g + 1) lo = m + 1; else hi = m; }
    float cn = (float)(lo - a);
    float inv = 1.0f / fmaxf(cn, 1.0f);
    float acc = 0.0f;
    for (int k = 0; k < H; k++)
        acc += pooled[g * H + k] * wlf[k * OUTF + o];
    float v = acc * inv + blf[o];
    if (*flag) ((float*)out)[g * OUTF + o] = v;
    else       ((unsigned short*)out)[g * OUTF + o] = gcn364_f2bf(v);
}

extern "C" void kernel_launch(void* const* d_in, const int* in_sizes, int n_in,
                              void* d_out, int out_size, void* d_ws, size_t ws_size,
                              hipStream_t stream) {
    const void* x  = d_in[0];
    const int* edge_index = (const int*)d_in[1];
    const int* batch      = (const int*)d_in[2];
    const void* W1 = d_in[3];
    const void* b1 = d_in[4];
    const void* W2 = d_in[5];
    const void* b2 = d_in[6];
    const void* Wl = d_in[7];
    const void* bl = d_in[8];

    const int N = in_sizes[0] / DIN;
    const int E = in_sizes[1] / 2;
    const int G = out_size / OUTF;
    const int* src = edge_index;
    const int* dst = edge_index + E;
    const int NB = (N + 1023) / 1024;   // scan blocks (must be <= 256)

    // ---- workspace layout; deg+pooled zeroed (contiguous at ws start) ----
    char* wsb = (char*)d_ws;
    int*   deg      = (int*)wsb;                                  // N      (zeroed)
    float* pooled   = (float*)(deg + N);                          // G*H    (zeroed)
    int*   off      = (int*)(pooled + (size_t)G * H);             // N
    int*   partials = off + N;                                    // 256
    int*   flag     = partials + 256;                             // 1
    size_t ofs = (((size_t)((char*)(flag + 1) - wsb)) + 15) & ~(size_t)15;
    float4* xf4 = (float4*)(wsb + ofs);                           // N float4
    float4* u4  = xf4 + N;                                        // N float4
    float* wf   = (float*)(u4 + N);                               // NWEIGHT
    int*   esrc = (int*)(wf + NWEIGHT);                           // E

    float* w1f = wf;
    float* b1f = w1f + 384;
    float* w2f = b1f + 128;
    float* b2f = w2f + 16384;
    float* wlf = b2f + 128;
    float* blf = wlf + 1280;

    hipMemsetAsync(d_ws, 0, ((size_t)N + (size_t)G * H) * 4, stream);

    {
        int total = N + NWEIGHT;
        int gmax = (E > total) ? E : total;
        gcn364_convdeg<<<(gmax + 255) / 256, 256, 0, stream>>>(
            x, W1, b1, W2, b2, Wl, bl, flag, xf4, wf, dst, deg, N, E);
    }
    gcn364_scan1<<<NB, 256, 0, stream>>>(deg, off, partials, xf4, N);
    gcn364_scan2<<<1, 256, 0, stream>>>(partials, NB);
    gcn364_fill<<<(E + 255) / 256, 256, 0, stream>>>(src, dst, off, partials, esrc, E);
    gcn364_aggu<<<(N + 15) / 16, 256, 0, stream>>>(esrc, off, partials, xf4, u4, N);
    gcn364_agg2pool<<<(N + MPB - 1) / MPB, 256, 0, stream>>>(
        esrc, off, partials, u4, w1f, b1f, w2f, b2f, batch, pooled, N);
    gcn364_final<<<G, 64, 0, stream>>>(pooled, batch, wlf, blf, flag, d_out, N, G);
}

// Round 11
// 352.830 us; speedup vs baseline: 1.2183x; 1.1747x over previous
//
#include <hip/hip_runtime.h>

// GCN: 2x GCNConv(+self-loop sym-norm) + ReLU, global mean pool, linear head.
// N=100000, E=1600000, G=100, D_IN=3, H=128, OUT=10.
//
// R10->R11: fill was #1 (144us, WRITE 106MB @ VALUBusy 0.4%): the counting
// sort scatter spreads each esrc cache line's ~16 writes across all 8 XCDs
// over the whole kernel -> ~16x write amplification via cross-XCD line
// ping-pong. Fix: XCD-AFFINE FILTERED FILL — 8 node-regions, block
// (slice, r=blockIdx&7) processes only dst in region r. With round-robin
// block->XCD dispatch each region's esrc+cursor lines live in ONE XCD's L2
// and write back once. Correctness does not depend on the mapping (regions
// partition nodes); only locality does. Everything else unchanged from R10.
//
// All kernels static + gcn364_ prefix (cross-.so symbol collisions caused the
// round-1 silent failure). Runtime dtype probe handles bf16/fp32 harness mode.

#define DIN 3
#define H 128
#define OUTF 10
#define NWEIGHT (384 + 128 + 16384 + 128 + 1280 + 10)  // W1,b1,W2,b2,Wl,bl

typedef float gcn364_f2 __attribute__((ext_vector_type(2)));

__device__ __forceinline__ float gcn364_bf2f(unsigned short u) {
    return __uint_as_float(((unsigned int)u) << 16);
}
__device__ __forceinline__ unsigned short gcn364_f2bf(float f) {
    unsigned int u = __float_as_uint(f);
    u += 0x7FFFu + ((u >> 16) & 1u);   // round-to-nearest-even
    return (unsigned short)(u >> 16);
}

// per-wave dtype probe over x's first 256 ushorts: 1 -> fp32, 0 -> bf16.
// bf16 N(0,1) exponents cluster in [101,129]; fp32 low-halves are ~uniform.
__device__ __forceinline__ int gcn364_probe(const unsigned short* __restrict__ xs16) {
    int lane = threadIdx.x & 63;
    int outl = 0;
    #pragma unroll
    for (int k = 0; k < 4; k++) {
        unsigned short u = xs16[lane * 4 + k];
        int e = (u >> 7) & 0xFF;
        outl += (e < 100 || e > 140) ? 1 : 0;
    }
    #pragma unroll
    for (int d = 1; d < 64; d <<= 1) outl += __shfl_xor(outl, d);
    return (outl > 32) ? 1 : 0;
}

// ---- convert x -> xf4 (float4/node) + weights -> wf + deg count + flag ----
static __global__ void gcn364_convdeg(const void* __restrict__ x,
                                      const void* __restrict__ W1, const void* __restrict__ b1,
                                      const void* __restrict__ W2, const void* __restrict__ b2,
                                      const void* __restrict__ Wl, const void* __restrict__ bl,
                                      int* __restrict__ flag,
                                      float4* __restrict__ xf4, float* __restrict__ wf,
                                      const int* __restrict__ edst, int* __restrict__ deg,
                                      int N, int E) {
    int fl = gcn364_probe((const unsigned short*)x);
    int i = blockIdx.x * blockDim.x + threadIdx.x;
    if (i == 0) *flag = fl;
    if (i < E) atomicAdd(&deg[edst[i]], 1);
    if (i < N) {
        float a, b, c;
        if (fl) {
            const float* xs = (const float*)x;
            a = xs[3 * i]; b = xs[3 * i + 1]; c = xs[3 * i + 2];
        } else {
            const unsigned short* xs = (const unsigned short*)x;
            a = gcn364_bf2f(xs[3 * i]); b = gcn364_bf2f(xs[3 * i + 1]); c = gcn364_bf2f(xs[3 * i + 2]);
        }
        xf4[i] = make_float4(a, b, c, 0.f);
    } else if (i < N + NWEIGHT) {
        int j = i - N;
        const void* srcp;
        if      (j < 384)                       { srcp = W1; }
        else if ((j -= 384)   < 128)            { srcp = b1; }
        else if ((j -= 128)   < 16384)          { srcp = W2; }
        else if ((j -= 16384) < 128)            { srcp = b2; }
        else if ((j -= 128)   < 1280)           { srcp = Wl; }
        else    { j -= 1280;                      srcp = bl; }
        wf[i - N] = fl ? ((const float*)srcp)[j]
                       : gcn364_bf2f(((const unsigned short*)srcp)[j]);
    }
}

// ---- exclusive scan of deg[N] -> off[N] (block-local) + dinvs/xf scaling ----
static __global__ void gcn364_scan1(const int* __restrict__ deg, int* __restrict__ off,
                                    int* __restrict__ partials, float4* __restrict__ xf4,
                                    int N) {
    __shared__ int sh[256];
    int t = threadIdx.x;
    int base = blockIdx.x * 1024 + t * 4;
    int v0 = (base + 0 < N) ? deg[base + 0] : 0;
    int v1 = (base + 1 < N) ? deg[base + 1] : 0;
    int v2 = (base + 2 < N) ? deg[base + 2] : 0;
    int v3 = (base + 3 < N) ? deg[base + 3] : 0;
    int s = v0 + v1 + v2 + v3;
    sh[t] = s;
    __syncthreads();
    for (int d = 1; d < 256; d <<= 1) {
        int val = (t >= d) ? sh[t - d] : 0;
        __syncthreads();
        sh[t] += val;
        __syncthreads();
    }
    int excl = sh[t] - s;
    int run = excl;
    if (base + 0 < N) off[base + 0] = run; run += v0;
    if (base + 1 < N) off[base + 1] = run; run += v1;
    if (base + 2 < N) off[base + 2] = run; run += v2;
    if (base + 3 < N) off[base + 3] = run;
    if (t == 255) partials[blockIdx.x] = sh[255];
    // dinvs + pre-scale xf by dinvs; dinvs rides in xf4.w
    int vv[4] = {v0, v1, v2, v3};
    #pragma unroll
    for (int k = 0; k < 4; k++) {
        int i = base + k;
        if (i < N) {
            float di = rsqrtf((float)vv[k] + 1.0f);
            float4 xv = xf4[i];
            xv.x *= di; xv.y *= di; xv.z *= di; xv.w = di;
            xf4[i] = xv;
        }
    }
}

// single block: exclusive scan of per-block partials
static __global__ void gcn364_scan2(int* __restrict__ partials, int nb) {
    __shared__ int sh[256];
    int t = threadIdx.x;
    int v = (t < nb) ? partials[t] : 0;
    sh[t] = v;
    __syncthreads();
    for (int d = 1; d < 256; d <<= 1) {
        int val = (t >= d) ? sh[t - d] : 0;
        __syncthreads();
        sh[t] += val;
        __syncthreads();
    }
    if (t < nb) partials[t] = sh[t] - v;   // exclusive
}

// XCD-affine filtered bucket fill. Grid = slices x 8 regions.
// Block (s, r=blockIdx&7) scans edge slice s, keeps edges with dst in node
// region r -> each region's esrc range + cursors are written from (nominally)
// one XCD only: lines collect all their writes in that XCD's L2.
// Afterwards off[i] + partials[i>>10] == end offset of node i.
#define FILL_CH 2048
static __global__ void gcn364_fill(const int* __restrict__ src, const int* __restrict__ dst,
                                   int* __restrict__ off, const int* __restrict__ partials,
                                   int* __restrict__ esrc, int E, int N) {
    int r = blockIdx.x & 7;
    int s = blockIdx.x >> 3;
    int regSize = (N + 7) >> 3;
    int rlo = r * regSize;
    int rhi = rlo + regSize;
    int elo = s * FILL_CH;
    int ehi = elo + FILL_CH;
    if (ehi > E) ehi = E;
    for (int e = elo + threadIdx.x; e < ehi; e += 256) {
        int d = dst[e];
        if (d >= rlo && d < rhi) {
            int p = atomicAdd(&off[d], 1) + partials[d >> 10];
            esrc[p] = src[e];
        }
    }
}

// Layer-1 aggregation -> u4 records. 16 lanes per node, 4 nodes per wave.
// xf4 pre-scaled by dinvs (dinvs in .w). One float4 load per edge.
static __global__ void gcn364_aggu(const int* __restrict__ esrc,
                                   const int* __restrict__ off,
                                   const int* __restrict__ partials,
                                   const float4* __restrict__ xf4,
                                   float4* __restrict__ u4, int N) {
    int lane = threadIdx.x & 63;
    int wv = threadIdx.x >> 6;
    int grp = lane >> 4;
    int sub = lane & 15;
    int i = (blockIdx.x * 4 + wv) * 4 + grp;

    float a0 = 0.f, a1 = 0.f, a2 = 0.f;
    if (i < N) {
        int p0 = (i == 0) ? 0 : off[i - 1] + partials[(i - 1) >> 10];
        int p1 = off[i] + partials[i >> 10];
        for (int p = p0 + sub; p < p1; p += 16) {
            float4 sv = xf4[esrc[p]];
            a0 += sv.x; a1 += sv.y; a2 += sv.z;
        }
    }
    for (int d = 1; d < 16; d <<= 1) {
        a0 += __shfl_xor(a0, d);
        a1 += __shfl_xor(a1, d);
        a2 += __shfl_xor(a2, d);
    }
    if (i < N && sub == 0) {
        float4 xi = xf4[i];
        float di = xi.w;
        u4[i] = make_float4(di * (a0 + xi.x), di * (a1 + xi.y), di * (a2 + xi.z), di);
    }
}

// per-edge layer-1 row recompute + accumulate (packed dual-fp32)
__device__ __forceinline__ void gcn364_edge(const float4 u,
                                            const gcn364_f2* wa2, const gcn364_f2* wb2,
                                            const gcn364_f2* wc2, const gcn364_f2* bb2,
                                            gcn364_f2* acc) {
    gcn364_f2 ux = {u.x, u.x}, uy = {u.y, u.y}, uz = {u.z, u.z}, uw = {u.w, u.w};
    gcn364_f2 zero = {0.f, 0.f};
    #pragma unroll
    for (int q = 0; q < 4; q++) {
        gcn364_f2 t = ux * wa2[q] + uy * wb2[q] + uz * wc2[q] + bb2[q];
        t = __builtin_elementwise_max(t, zero);
        acc[q] += uw * t;
    }
}

// Fused layer-2: per-edge on-the-fly layer-1 recompute + aggregation + GEMM +
// relu + mean-pool. MPB=16 nodes/block, 256 thr = 16 groups x 16 lanes,
// group-per-node (R8 tiling), packed dual-fp32 (R9 math).
#define MPB 16
static __global__ __launch_bounds__(256, 8) void gcn364_agg2pool(
        const int* __restrict__ esrc, const int* __restrict__ off,
        const int* __restrict__ partials, const float4* __restrict__ u4,
        const float* __restrict__ w1f, const float* __restrict__ b1f,
        const float* __restrict__ w2f, const float* __restrict__ b2f,
        const int* __restrict__ batch, float* __restrict__ pooled, int N) {
    __shared__ float vsh[MPB][H];
    int i0 = blockIdx.x * MPB;
    int tid = threadIdx.x;
    int wave = tid >> 6;
    int lane = tid & 63;
    int grp = lane >> 4;
    int sub = lane & 15;
    int node = wave * 4 + grp;
    int i = i0 + node;

    gcn364_f2 wa2[4], wb2[4], wc2[4], bb2[4];
    #pragma unroll
    for (int q = 0; q < 4; q++) {
        int f = sub * 8 + q * 2;
        wa2[q] = (gcn364_f2){w1f[f], w1f[f + 1]};
        wb2[q] = (gcn364_f2){w1f[H + f], w1f[H + f + 1]};
        wc2[q] = (gcn364_f2){w1f[2 * H + f], w1f[2 * H + f + 1]};
        bb2[q] = (gcn364_f2){b1f[f], b1f[f + 1]};
    }

    gcn364_f2 acc[4];
    acc[0] = acc[1] = acc[2] = acc[3] = (gcn364_f2){0.f, 0.f};
    float di = 0.f;
    if (i < N) {
        int p0 = (i == 0) ? 0 : off[i - 1] + partials[(i - 1) >> 10];
        int p1 = off[i] + partials[i >> 10];
        int p = p0;
        for (; p + 2 <= p1; p += 2) {
            float4 uA = u4[esrc[p]];
            float4 uB = u4[esrc[p + 1]];
            gcn364_edge(uA, wa2, wb2, wc2, bb2, acc);
            gcn364_edge(uB, wa2, wb2, wc2, bb2, acc);
        }
        if (p < p1) {
            float4 uA = u4[esrc[p]];
            gcn364_edge(uA, wa2, wb2, wc2, bb2, acc);
        }
        float4 uS = u4[i];   // self-loop
        gcn364_edge(uS, wa2, wb2, wc2, bb2, acc);
        di = uS.w;
    }
    *(float4*)&vsh[node][sub * 8 + 0] =
        make_float4(acc[0].x * di, acc[0].y * di, acc[1].x * di, acc[1].y * di);
    *(float4*)&vsh[node][sub * 8 + 4] =
        make_float4(acc[2].x * di, acc[2].y * di, acc[3].x * di, acc[3].y * di);
    __syncthreads();

    int f = tid & (H - 1);
    int half = tid >> 7;
    float bb = b2f[f];
    gcn364_f2 a2[8];
    #pragma unroll
    for (int n = 0; n < 8; n++) a2[n] = (gcn364_f2){0.f, 0.f};
    for (int k4 = 0; k4 < H / 4; k4++) {
        gcn364_f2 wlo = {w2f[(k4 * 4 + 0) * H + f], w2f[(k4 * 4 + 1) * H + f]};
        gcn364_f2 whi = {w2f[(k4 * 4 + 2) * H + f], w2f[(k4 * 4 + 3) * H + f]};
        #pragma unroll
        for (int n = 0; n < 8; n++) {
            float4 v = *(const float4*)&vsh[2 * n + half][k4 * 4];
            a2[n] += (gcn364_f2){v.x, v.y} * wlo + (gcn364_f2){v.z, v.w} * whi;
        }
    }

    float sum = 0.0f;
    int curg = -1;
    #pragma unroll
    for (int j = 0; j < 8; j++) {
        int ii = i0 + half + 2 * j;
        if (ii >= N) continue;
        float val = fmaxf(a2[j].x + a2[j].y + bb, 0.0f);
        int g = batch[ii];
        if (g != curg) {
            if (curg >= 0) atomicAdd(&pooled[curg * H + f], sum);
            curg = g;
            sum = 0.0f;
        }
        sum += val;
    }
    if (curg >= 0) atomicAdd(&pooled[curg * H + f], sum);
}

// out[g] = (pooled[g]/cnt_g) @ Wl + bl  -> detected dtype.
// cnt_g computed here via binary search on the sorted batch array.
static __global__ void gcn364_final(const float* __restrict__ pooled,
                                    const int* __restrict__ batch,
                                    const float* __restrict__ wlf,
                                    const float* __restrict__ blf,
                                    const int* __restrict__ flag,
                                    void* __restrict__ out, int N, int G) {
    int g = blockIdx.x;
    int o = threadIdx.x;
    if (g >= G || o >= OUTF) return;
    int lo = 0, hi = N;
    while (lo < hi) { int m = (lo + hi) >> 1; if (batch[m] < g) lo = m + 1; else hi = m; }
    int a = lo;
    lo = 0; hi = N;
    while (lo < hi) { int m = (lo + hi) >> 1; if (batch[m] < g + 1) lo = m + 1; else hi = m; }
    float cn = (float)(lo - a);
    float inv = 1.0f / fmaxf(cn, 1.0f);
    float acc = 0.0f;
    for (int k = 0; k < H; k++)
        acc += pooled[g * H + k] * wlf[k * OUTF + o];
    float v = acc * inv + blf[o];
    if (*flag) ((float*)out)[g * OUTF + o] = v;
    else       ((unsigned short*)out)[g * OUTF + o] = gcn364_f2bf(v);
}

extern "C" void kernel_launch(void* const* d_in, const int* in_sizes, int n_in,
                              void* d_out, int out_size, void* d_ws, size_t ws_size,
                              hipStream_t stream) {
    const void* x  = d_in[0];
    const int* edge_index = (const int*)d_in[1];
    const int* batch      = (const int*)d_in[2];
    const void* W1 = d_in[3];
    const void* b1 = d_in[4];
    const void* W2 = d_in[5];
    const void* b2 = d_in[6];
    const void* Wl = d_in[7];
    const void* bl = d_in[8];

    const int N = in_sizes[0] / DIN;
    const int E = in_sizes[1] / 2;
    const int G = out_size / OUTF;
    const int* src = edge_index;
    const int* dst = edge_index + E;
    const int NB = (N + 1023) / 1024;   // scan blocks (must be <= 256)

    // ---- workspace layout; deg+pooled zeroed (contiguous at ws start) ----
    char* wsb = (char*)d_ws;
    int*   deg      = (int*)wsb;                                  // N      (zeroed)
    float* pooled   = (float*)(deg + N);                          // G*H    (zeroed)
    int*   off      = (int*)(pooled + (size_t)G * H);             // N
    int*   partials = off + N;                                    // 256
    int*   flag     = partials + 256;                             // 1
    size_t ofs = (((size_t)((char*)(flag + 1) - wsb)) + 15) & ~(size_t)15;
    float4* xf4 = (float4*)(wsb + ofs);                           // N float4
    float4* u4  = xf4 + N;                                        // N float4
    float* wf   = (float*)(u4 + N);                               // NWEIGHT
    int*   esrc = (int*)(wf + NWEIGHT);                           // E

    float* w1f = wf;
    float* b1f = w1f + 384;
    float* w2f = b1f + 128;
    float* b2f = w2f + 16384;
    float* wlf = b2f + 128;
    float* blf = wlf + 1280;

    hipMemsetAsync(d_ws, 0, ((size_t)N + (size_t)G * H) * 4, stream);

    {
        int total = N + NWEIGHT;
        int gmax = (E > total) ? E : total;
        gcn364_convdeg<<<(gmax + 255) / 256, 256, 0, stream>>>(
            x, W1, b1, W2, b2, Wl, bl, flag, xf4, wf, dst, deg, N, E);
    }
    gcn364_scan1<<<NB, 256, 0, stream>>>(deg, off, partials, xf4, N);
    gcn364_scan2<<<1, 256, 0, stream>>>(partials, NB);
    {
        int S = (E + FILL_CH - 1) / FILL_CH;
        gcn364_fill<<<S * 8, 256, 0, stream>>>(src, dst, off, partials, esrc, E, N);
    }
    gcn364_aggu<<<(N + 15) / 16, 256, 0, stream>>>(esrc, off, partials, xf4, u4, N);
    gcn364_agg2pool<<<(N + MPB - 1) / MPB, 256, 0, stream>>>(
        esrc, off, partials, u4, w1f, b1f, w2f, b2f, batch, pooled, N);
    gcn364_final<<<G, 64, 0, stream>>>(pooled, batch, wlf, blf, flag, d_out, N, G);
}